// Round 7
// baseline (167.999 us; speedup 1.0000x reference)
//
#include <hip/hip_runtime.h>
#include <cstdint>

// CapsuleLayer dynamic routing: B=256, R=1152, C=10, O=16, I=8, 3 iters.
// fp32 in, fp32 out (verified round 6). Decomposes over (b,c); one block
// per (b,c). u[r,:] cached in LDS as packed bf16 pairs (stride 8 words,
// 16B-aligned -> ds_read_b128). Pass 0 (uniform softmax) fused into the
// u-compute phase via register accumulation. b_ij never stored: with b0=0,
// logit_k = u . (v0 + ... + v_{k-1}).
#define BB 256
#define RR 1152
#define CC 10
#define OO 16
#define II 8
#define NT 256

__device__ __forceinline__ uint32_t f2bf(float f) {
    union { float f; uint32_t i; } v; v.f = f;
    return (v.i + 0x7fffu + ((v.i >> 16) & 1u)) >> 16;   // RNE
}
__device__ __forceinline__ void unpack2(uint32_t pk, float& lo, float& hi) {
    union { uint32_t i; float f; } a, b;
    a.i = pk << 16; b.i = pk & 0xffff0000u;
    lo = a.f; hi = b.f;
}

__global__ __launch_bounds__(NT)
void k_caps(const float* __restrict__ x, const float* __restrict__ W,
            float* __restrict__ out) {
    __shared__ uint32_t u_lds[RR * 8];   // packed bf16 pairs: 36,864 B
    __shared__ float part[4][17];
    __shared__ float p0[4][8][2];
    __shared__ float sarr[OO];
    __shared__ float wsumv[OO];

    const int t = threadIdx.x;
    const int c = blockIdx.x >> 8;    // c-major: 256 consecutive blocks share W-slice
    const int b = blockIdx.x & 255;
    const int rl = t >> 3;            // r-lane 0..31
    const int p  = t & 7;             // o-pair 0..7 (o = 2p, 2p+1)
    const int wv = t >> 6, l = t & 63;

    // ---- Phase 1: u[r, 2p:2p+2] -> LDS packed; fused pass-0 sum in regs ----
    float s0lo = 0.f, s0hi = 0.f;
    for (int it = 0; it < RR / 32; ++it) {
        const int r = it * 32 + rl;
        const float* wp = W + (((size_t)r * CC + c) * OO + 2 * p) * II;
        const float* xp = x + ((size_t)b * RR + r) * II;   // 8 lanes share -> broadcast
        float4 x0 = *reinterpret_cast<const float4*>(xp);
        float4 x1 = *reinterpret_cast<const float4*>(xp + 4);
        float4 a0 = *reinterpret_cast<const float4*>(wp);
        float4 a1 = *reinterpret_cast<const float4*>(wp + 4);
        float4 b0 = *reinterpret_cast<const float4*>(wp + 8);
        float4 b1 = *reinterpret_cast<const float4*>(wp + 12);
        float ulo = 0.f, uhi = 0.f;
        ulo = fmaf(a0.x, x0.x, ulo); ulo = fmaf(a0.y, x0.y, ulo);
        ulo = fmaf(a0.z, x0.z, ulo); ulo = fmaf(a0.w, x0.w, ulo);
        ulo = fmaf(a1.x, x1.x, ulo); ulo = fmaf(a1.y, x1.y, ulo);
        ulo = fmaf(a1.z, x1.z, ulo); ulo = fmaf(a1.w, x1.w, ulo);
        uhi = fmaf(b0.x, x0.x, uhi); uhi = fmaf(b0.y, x0.y, uhi);
        uhi = fmaf(b0.z, x0.z, uhi); uhi = fmaf(b0.w, x0.w, uhi);
        uhi = fmaf(b1.x, x1.x, uhi); uhi = fmaf(b1.y, x1.y, uhi);
        uhi = fmaf(b1.z, x1.z, uhi); uhi = fmaf(b1.w, x1.w, uhi);
        s0lo += ulo; s0hi += uhi;
        u_lds[r * 8 + p] = f2bf(ulo) | (f2bf(uhi) << 16);  // banks (8rl+p)%32: 2-way, free
    }
    // reduce pass-0 sums across the 8 r-lanes of this wave (lanes sharing p)
#pragma unroll
    for (int m = 8; m < 64; m <<= 1) {
        s0lo += __shfl_xor(s0lo, m);
        s0hi += __shfl_xor(s0hi, m);
    }
    if (l < 8) { p0[wv][l][0] = s0lo; p0[wv][l][1] = s0hi; }
    __syncthreads();

    if (t < OO) {   // t = o = 2*(t>>1)+(t&1)
        float s = 0.f;
#pragma unroll
        for (int j = 0; j < 4; ++j) s += p0[j][t >> 1][t & 1];
        sarr[t] = s * (1.0f / RR);   // softmax(0) = 1/R
    }
    __syncthreads();
    if (t < OO) {
        float ss = 0.f;
#pragma unroll
        for (int j = 0; j < OO; ++j) ss += sarr[j] * sarr[j];
        float s = sarr[t];
        wsumv[t] = s * (ss / ((1.0f + ss) * sqrtf(ss + 1e-7f)));  // v0
    }
    __syncthreads();

    // ---- Phase 2: two exp passes from LDS (b128 packed reads) ----
    for (int pass = 1; pass < 3; ++pass) {
        float wreg[OO];
#pragma unroll
        for (int k = 0; k < OO; ++k) wreg[k] = wsumv[k];
        float num[OO];
#pragma unroll
        for (int k = 0; k < OO; ++k) num[k] = 0.f;
        float den = 0.f;

        for (int r = t; r < RR; r += NT) {
            uint4 q0 = *reinterpret_cast<const uint4*>(&u_lds[r * 8]);
            uint4 q1 = *reinterpret_cast<const uint4*>(&u_lds[r * 8 + 4]);
            float ur[OO];
            unpack2(q0.x, ur[0], ur[1]);   unpack2(q0.y, ur[2], ur[3]);
            unpack2(q0.z, ur[4], ur[5]);   unpack2(q0.w, ur[6], ur[7]);
            unpack2(q1.x, ur[8], ur[9]);   unpack2(q1.y, ur[10], ur[11]);
            unpack2(q1.z, ur[12], ur[13]); unpack2(q1.w, ur[14], ur[15]);
            float lg = 0.f;
#pragma unroll
            for (int k = 0; k < OO; ++k) lg = fmaf(ur[k], wreg[k], lg);
            float e = __expf(lg);   // |logit| <~ 50: fp32-safe, no max-sub
            den += e;
#pragma unroll
            for (int k = 0; k < OO; ++k) num[k] = fmaf(e, ur[k], num[k]);
        }

#pragma unroll
        for (int m = 1; m < 64; m <<= 1) {
#pragma unroll
            for (int k = 0; k < OO; ++k) num[k] += __shfl_xor(num[k], m);
            den += __shfl_xor(den, m);
        }
        if (l == 0) {
#pragma unroll
            for (int k = 0; k < OO; ++k) part[wv][k] = num[k];
            part[wv][16] = den;
        }
        __syncthreads();
        if (t < OO) {
            float nf = 0.f, df = 0.f;
#pragma unroll
            for (int j = 0; j < 4; ++j) { nf += part[j][t]; df += part[j][16]; }
            sarr[t] = nf / df;
        }
        __syncthreads();
        if (t < OO) {
            float ss = 0.f;
#pragma unroll
            for (int j = 0; j < OO; ++j) ss += sarr[j] * sarr[j];
            float s = sarr[t];
            float v = s * (ss / ((1.0f + ss) * sqrtf(ss + 1e-7f)));
            if (pass == 2) out[(size_t)b * (CC * OO) + c * OO + t] = v;
            else wsumv[t] += v;
        }
        __syncthreads();
    }
}

extern "C" void kernel_launch(void* const* d_in, const int* in_sizes, int n_in,
                              void* d_out, int out_size, void* d_ws, size_t ws_size,
                              hipStream_t stream) {
    const float* x = (const float*)d_in[0];  // (B,R,I) fp32
    const float* W = (const float*)d_in[1];  // (R,C,O,I) fp32
    if (n_in >= 2 && in_sizes[0] == RR * CC * OO * II &&
        in_sizes[1] == BB * RR * II) {
        const float* tmp = x; x = W; W = tmp;
    }
    float* out = (float*)d_out;              // (B,1,C,O,1) fp32

    k_caps<<<BB * CC, NT, 0, stream>>>(x, W, out);
}